// Round 1
// baseline (194.983 us; speedup 1.0000x reference)
//
#include <hip/hip_runtime.h>
#include <math.h>

#define C_DIM 4
#define T_DIM 4096
#define D_DIM 1024
#define E_DIM 16
#define CAP   320
#define CT    (C_DIM * T_DIM)          // 16384 tokens
#define OUT_ONE ((size_t)CT * E_DIM * CAP)  // 83,886,080 elements per big output

// ws layout (bytes):
//   0      : auxpart f32[64]   (atomic accumulation of softmax prob sums per (c,e)) - zeroed each call
//   256    : counts  i32[64]   (full pre-truncation argmax counts per (c,e))
//   512    : gate    f32[CT]
//   66048  : index   i32[CT]
//   131584 : rank    i32[CT]   (1-based rank of token within its chosen expert)

// ---------------------------------------------------------------------------
// Kernel A: fused jitter * input, router logits (16 dots of length 1024),
// softmax, argmax/gate, and prob-sum accumulation for the aux loss.
// One wave handles 4 tokens; block = 256 threads = 4 waves = 16 tokens.
// W (16x1024 f32 = 64KB) stays hot in L2; reads are fully coalesced.
// ---------------------------------------------------------------------------
__global__ __launch_bounds__(256) void router_logits_kernel(
    const float* __restrict__ in, const float* __restrict__ w,
    const float* __restrict__ noise, float* __restrict__ gate,
    int* __restrict__ index, float* __restrict__ auxpart)
{
    __shared__ float psum[E_DIM];
    const int tid  = threadIdx.x;
    if (tid < E_DIM) psum[tid] = 0.0f;
    __syncthreads();

    const int wave = tid >> 6;
    const int lane = tid & 63;
    const int g0   = blockIdx.x * 16 + wave * 4;   // first of 4 tokens for this wave

    float acc[4][16];
    #pragma unroll
    for (int tk = 0; tk < 4; ++tk)
        #pragma unroll
        for (int e = 0; e < 16; ++e)
            acc[tk][e] = 0.0f;

    #pragma unroll
    for (int r = 0; r < 4; ++r) {
        const int d0 = r * 256 + lane * 4;
        float4 x[4];
        #pragma unroll
        for (int tk = 0; tk < 4; ++tk) {
            const float4 a = *(const float4*)(in    + (size_t)(g0 + tk) * D_DIM + d0);
            const float4 n = *(const float4*)(noise + (size_t)(g0 + tk) * D_DIM + d0);
            x[tk] = make_float4(a.x * n.x, a.y * n.y, a.z * n.z, a.w * n.w);
        }
        #pragma unroll
        for (int e = 0; e < 16; ++e) {
            const float4 wv = *(const float4*)(w + e * D_DIM + d0);
            #pragma unroll
            for (int tk = 0; tk < 4; ++tk) {
                acc[tk][e] += x[tk].x * wv.x + x[tk].y * wv.y
                            + x[tk].z * wv.z + x[tk].w * wv.w;
            }
        }
    }

    // reduce the 16 partial dots across the 64 lanes
    #pragma unroll
    for (int tk = 0; tk < 4; ++tk)
        #pragma unroll
        for (int e = 0; e < 16; ++e)
            #pragma unroll
            for (int off = 32; off; off >>= 1)
                acc[tk][e] += __shfl_down(acc[tk][e], off, 64);

    if (lane == 0) {
        #pragma unroll
        for (int tk = 0; tk < 4; ++tk) {
            const int g = g0 + tk;
            float m = -1e30f; int am = 0;
            #pragma unroll
            for (int e = 0; e < 16; ++e)
                if (acc[tk][e] > m) { m = acc[tk][e]; am = e; }
            float p[16]; float s = 0.0f;
            #pragma unroll
            for (int e = 0; e < 16; ++e) { p[e] = __expf(acc[tk][e] - m); s += p[e]; }
            const float inv = 1.0f / s;
            gate[g]  = inv;          // probs[argmax] = exp(0)/s
            index[g] = am;
            #pragma unroll
            for (int e = 0; e < 16; ++e)
                atomicAdd(&psum[e], p[e] * inv);
        }
    }
    __syncthreads();
    if (tid < 16) {
        const int c = blockIdx.x / 256;   // 256 blocks per c (4096 tokens / 16)
        atomicAdd(&auxpart[c * 16 + tid], psum[tid]);
    }
}

// ---------------------------------------------------------------------------
// Kernel B: per-c rank (cumsum of one-hot over T) + full per-expert counts.
// One block per c; 256 threads x 16 tokens each; chunked histogram + scan.
// ---------------------------------------------------------------------------
__global__ __launch_bounds__(256) void rank_kernel(
    const int* __restrict__ index, int* __restrict__ rank, int* __restrict__ counts)
{
    __shared__ int hist[256 * 16];
    const int tid = threadIdx.x;
    const int c   = blockIdx.x;
    const int* idxrow = index + c * T_DIM;
    const int base = tid * 16;

    #pragma unroll
    for (int e = 0; e < 16; ++e) hist[base + e] = 0;
    __syncthreads();

    for (int j = 0; j < 16; ++j) {
        const int e = idxrow[base + j];
        hist[base + e] += 1;
    }
    __syncthreads();

    if (tid < 16) {
        int running = 0;
        for (int i = 0; i < 256; ++i) {
            const int v = hist[i * 16 + tid];
            hist[i * 16 + tid] = running;
            running += v;
        }
        counts[c * 16 + tid] = running;   // pre-truncation count (for density1)
    }
    __syncthreads();

    for (int j = 0; j < 16; ++j) {
        const int t = base + j;
        const int e = idxrow[t];
        const int r = hist[base + e] + 1;   // 1-based rank within expert e
        hist[base + e] = r;
        rank[c * T_DIM + t] = r;
    }
}

// ---------------------------------------------------------------------------
// Kernel C: scatter the <=64 nonzeros of dispatch/combine + aux loss.
// Single wave of 64 threads; id = c*16 + t' (t' = token position < 16,
// flagged iff expert value t' appears as an argmax in row c).
// ---------------------------------------------------------------------------
__global__ __launch_bounds__(64) void finalize_kernel(
    const float* __restrict__ gate, const int* __restrict__ index,
    const int* __restrict__ rank, const int* __restrict__ counts,
    const float* __restrict__ auxpart, float* __restrict__ out)
{
    const int id = threadIdx.x;          // 0..63
    const int c  = id >> 4;
    const int tp = id & 15;
    const int cnt = counts[id];

    // aux term: density1 * density1_proxy for this (c,e)
    float term = ((float)cnt * (1.0f / T_DIM)) * (auxpart[id] * (1.0f / T_DIM));

    if (cnt > 0) {
        const int g  = c * T_DIM + tp;
        const int rk = rank[g];
        if (rk < CAP) {                       // kept within capacity
            const int idx = index[g];
            const int s   = (idx == 0) ? rk : 0;  // position_in_expert[c,t,0]
            const size_t off = ((size_t)g * E_DIM + 0) * CAP + (size_t)s;
            out[off]            = 1.0f;       // dispatch
            out[OUT_ONE + off]  = gate[g];    // combine
        }
    }

    #pragma unroll
    for (int off = 32; off; off >>= 1)
        term += __shfl_down(term, off, 64);
    if (id == 0)
        out[2 * OUT_ONE] = 16.0f * term;      // aux_loss = E * sum(density1*proxy)
}

extern "C" void kernel_launch(void* const* d_in, const int* in_sizes, int n_in,
                              void* d_out, int out_size, void* d_ws, size_t ws_size,
                              hipStream_t stream) {
    const float* in    = (const float*)d_in[0];
    const float* w     = (const float*)d_in[1];
    const float* noise = (const float*)d_in[2];
    float* out = (float*)d_out;

    char* ws = (char*)d_ws;
    float* auxpart = (float*)(ws);
    int*   counts  = (int*)(ws + 256);
    float* gate    = (float*)(ws + 512);
    int*   index   = (int*)(ws + 512 + 65536);
    int*   rank    = (int*)(ws + 512 + 131072);

    // Zero the (mostly-zero) 671MB output and the atomic accumulators.
    hipMemsetAsync(d_out, 0, (size_t)out_size * sizeof(float), stream);
    hipMemsetAsync(ws, 0, 256, stream);

    router_logits_kernel<<<dim3(CT / 16), dim3(256), 0, stream>>>(in, w, noise, gate, index, auxpart);
    rank_kernel<<<dim3(C_DIM), dim3(256), 0, stream>>>(index, rank, counts);
    finalize_kernel<<<dim3(1), dim3(64), 0, stream>>>(gate, index, rank, counts, auxpart, out);
}